// Round 1
// baseline (120.069 us; speedup 1.0000x reference)
//
#include <hip/hip_runtime.h>

#define SLOPE 0.2f

__device__ __forceinline__ float leaky(float v) {
    return v > 0.0f ? v : SLOPE * v;
}

__device__ __forceinline__ float fast_tanh(float v) {
    // tanh(x) = 1 - 2/(exp(2x)+1); exp via v_exp_f32, rcp via v_rcp_f32.
    // Saturates correctly: x>>0 -> e=inf -> rcp=0 -> 1; x<<0 -> e=0 -> -1.
    float e = __expf(2.0f * v);
    return 1.0f - 2.0f * __builtin_amdgcn_rcpf(e + 1.0f);
}

__global__ __launch_bounds__(256) void minigen_kernel(
    const float* __restrict__ x,
    const float* __restrict__ w1, const float* __restrict__ b1,
    const float* __restrict__ w2, const float* __restrict__ b2,
    const float* __restrict__ w3, const float* __restrict__ b3,
    const float* __restrict__ w4, const float* __restrict__ b4,
    float* __restrict__ out, int n)
{
    int i = blockIdx.x * blockDim.x + threadIdx.x;
    if (i >= n) return;

    // ---- load x[2][16] : 32 contiguous floats, 8x float4 ----
    float xr[32];
    const float4* xin = (const float4*)(x + (size_t)i * 32);
#pragma unroll
    for (int q = 0; q < 8; ++q) {
        float4 v = xin[q];
        xr[4*q+0] = v.x; xr[4*q+1] = v.y; xr[4*q+2] = v.z; xr[4*q+3] = v.w;
    }

    // ---- conv1: [2,16] -> [4,8], stride 2, pad 1, leaky ----
    float e1[4][8];
#pragma unroll
    for (int oc = 0; oc < 4; ++oc) {
#pragma unroll
        for (int ol = 0; ol < 8; ++ol) {
            float s = b1[oc];
#pragma unroll
            for (int ic = 0; ic < 2; ++ic) {
#pragma unroll
                for (int k = 0; k < 3; ++k) {
                    int j = 2*ol - 1 + k;            // pad=1
                    if (j >= 0 && j < 16)            // constant-folds after unroll
                        s += xr[ic*16 + j] * w1[(oc*2 + ic)*3 + k];
                }
            }
            e1[oc][ol] = leaky(s);
        }
    }

    // ---- conv2: [4,8] -> [8,4], stride 2, pad 1, leaky ----
    float bn[8][4];
#pragma unroll
    for (int oc = 0; oc < 8; ++oc) {
#pragma unroll
        for (int ol = 0; ol < 4; ++ol) {
            float s = b2[oc];
#pragma unroll
            for (int ic = 0; ic < 4; ++ic) {
#pragma unroll
                for (int k = 0; k < 3; ++k) {
                    int j = 2*ol - 1 + k;
                    if (j >= 0 && j < 8)
                        s += e1[ic][j] * w2[(oc*4 + ic)*3 + k];
                }
            }
            bn[oc][ol] = leaky(s);
        }
    }

    // ---- up1 (x2 nearest) + conv3: [8,8] -> [4,8], stride 1, pad 1,
    //      leaky, then skip-add enc1 ----
    float sk[4][8];
#pragma unroll
    for (int oc = 0; oc < 4; ++oc) {
#pragma unroll
        for (int ol = 0; ol < 8; ++ol) {
            float s = b3[oc];
#pragma unroll
            for (int ic = 0; ic < 8; ++ic) {
#pragma unroll
                for (int k = 0; k < 3; ++k) {
                    int j = ol - 1 + k;
                    if (j >= 0 && j < 8)
                        s += bn[ic][j >> 1] * w3[(oc*8 + ic)*3 + k];
                }
            }
            sk[oc][ol] = leaky(s) + e1[oc][ol];
        }
    }

    // ---- up2 (x2 nearest) + conv4: [4,16] -> [2,16], stride 1, pad 1, tanh ----
    float o[32];
#pragma unroll
    for (int oc = 0; oc < 2; ++oc) {
#pragma unroll
        for (int ol = 0; ol < 16; ++ol) {
            float s = b4[oc];
#pragma unroll
            for (int ic = 0; ic < 4; ++ic) {
#pragma unroll
                for (int k = 0; k < 3; ++k) {
                    int j = ol - 1 + k;
                    if (j >= 0 && j < 16)
                        s += sk[ic][j >> 1] * w4[(oc*4 + ic)*3 + k];
                }
            }
            o[oc*16 + ol] = fast_tanh(s);
        }
    }

    // ---- store out[2][16] : 32 contiguous floats, 8x float4 ----
    float4* op = (float4*)(out + (size_t)i * 32);
#pragma unroll
    for (int q = 0; q < 8; ++q) {
        op[q] = make_float4(o[4*q+0], o[4*q+1], o[4*q+2], o[4*q+3]);
    }
}

extern "C" void kernel_launch(void* const* d_in, const int* in_sizes, int n_in,
                              void* d_out, int out_size, void* d_ws, size_t ws_size,
                              hipStream_t stream) {
    const float* x  = (const float*)d_in[0];
    const float* w1 = (const float*)d_in[1];
    const float* b1 = (const float*)d_in[2];
    const float* w2 = (const float*)d_in[3];
    const float* b2 = (const float*)d_in[4];
    const float* w3 = (const float*)d_in[5];
    const float* b3 = (const float*)d_in[6];
    const float* w4 = (const float*)d_in[7];
    const float* b4 = (const float*)d_in[8];
    float* out = (float*)d_out;

    int n = in_sizes[0] / 32;           // B = 262144 samples
    const int block = 256;
    int grid = (n + block - 1) / block;
    hipLaunchKernelGGL(minigen_kernel, dim3(grid), dim3(block), 0, stream,
                       x, w1, b1, w2, b2, w3, b3, w4, b4, out, n);
}

// Round 2
// 107.217 us; speedup vs baseline: 1.1199x; 1.1199x over previous
//
#include <hip/hip_runtime.h>

#define SLOPE 0.2f

__device__ __forceinline__ float leaky(float v) {
    // slope < 1  =>  leaky(v) == max(v, 0.2*v); no vcc/cndmask chain
    return __builtin_fmaxf(v, SLOPE * v);
}

__device__ __forceinline__ float fast_tanh(float v) {
    // tanh(x) = 1 - 2/(exp(2x)+1); saturates correctly at +/-1.
    float e = __expf(2.0f * v);
    return 1.0f - 2.0f * __builtin_amdgcn_rcpf(e + 1.0f);
}

// One thread per sample (32 floats in, 32 out). Global<->LDS staging so all
// global memory ops are fully coalesced (lane i touches base + i*16B).
// LDS row = 9 float4 per sample (8 data + 1 pad) -> bank-group index
// (9*s + r) % 8 is uniform across lanes in every phase: only the inherent
// 8-bank-cycles of ds_*_b128, no extra conflicts.
__global__ __launch_bounds__(256) void minigen_kernel(
    const float* __restrict__ x,
    const float* __restrict__ w1, const float* __restrict__ b1,
    const float* __restrict__ w2, const float* __restrict__ b2,
    const float* __restrict__ w3, const float* __restrict__ b3,
    const float* __restrict__ w4, const float* __restrict__ b4,
    float* __restrict__ out, int n)
{
    __shared__ float4 lds[256 * 9];              // 36 KB

    const int t = threadIdx.x;
    const int sample = blockIdx.x * 256 + t;
    const long long f4total = (long long)n * 8;  // total float4 in x/out
    const long long blockBase = (long long)blockIdx.x * 2048;  // f4 units

    // ---- stage in: coalesced global -> LDS ----
    const float4* xin = (const float4*)x;
#pragma unroll
    for (int q = 0; q < 8; ++q) {
        int g = q * 256 + t;                     // f4 index within block tile
        if (blockBase + g < f4total) {
            float4 v = xin[blockBase + g];
            int s = g >> 3, r = g & 7;
            lds[s * 9 + r] = v;
        }
    }
    __syncthreads();

    // ---- own sample: LDS -> registers ----
    float xr[32];
#pragma unroll
    for (int r = 0; r < 8; ++r) {
        float4 v = lds[t * 9 + r];
        xr[4*r+0] = v.x; xr[4*r+1] = v.y; xr[4*r+2] = v.z; xr[4*r+3] = v.w;
    }

    float o[32];
    if (sample < n) {
        // ---- conv1: [2,16] -> [4,8], stride 2, pad 1, leaky ----
        float e1[4][8];
#pragma unroll
        for (int oc = 0; oc < 4; ++oc) {
#pragma unroll
            for (int ol = 0; ol < 8; ++ol) {
                float s = b1[oc];
#pragma unroll
                for (int ic = 0; ic < 2; ++ic) {
#pragma unroll
                    for (int k = 0; k < 3; ++k) {
                        int j = 2*ol - 1 + k;
                        if (j >= 0 && j < 16)
                            s = fmaf(xr[ic*16 + j], w1[(oc*2 + ic)*3 + k], s);
                    }
                }
                e1[oc][ol] = leaky(s);
            }
        }

        // ---- conv2: [4,8] -> [8,4], stride 2, pad 1, leaky ----
        float bn[8][4];
#pragma unroll
        for (int oc = 0; oc < 8; ++oc) {
#pragma unroll
            for (int ol = 0; ol < 4; ++ol) {
                float s = b2[oc];
#pragma unroll
                for (int ic = 0; ic < 4; ++ic) {
#pragma unroll
                    for (int k = 0; k < 3; ++k) {
                        int j = 2*ol - 1 + k;
                        if (j >= 0 && j < 8)
                            s = fmaf(e1[ic][j], w2[(oc*4 + ic)*3 + k], s);
                    }
                }
                bn[oc][ol] = leaky(s);
            }
        }

        // ---- up1(x2) + conv3: [8,8] -> [4,8], s1 p1, leaky, +skip e1 ----
        float sk[4][8];
#pragma unroll
        for (int oc = 0; oc < 4; ++oc) {
#pragma unroll
            for (int ol = 0; ol < 8; ++ol) {
                float s = b3[oc];
#pragma unroll
                for (int ic = 0; ic < 8; ++ic) {
#pragma unroll
                    for (int k = 0; k < 3; ++k) {
                        int j = ol - 1 + k;
                        if (j >= 0 && j < 8)
                            s = fmaf(bn[ic][j >> 1], w3[(oc*8 + ic)*3 + k], s);
                    }
                }
                sk[oc][ol] = leaky(s) + e1[oc][ol];
            }
        }

        // ---- up2(x2) + conv4: [4,16] -> [2,16], s1 p1, tanh ----
#pragma unroll
        for (int oc = 0; oc < 2; ++oc) {
#pragma unroll
            for (int ol = 0; ol < 16; ++ol) {
                float s = b4[oc];
#pragma unroll
                for (int ic = 0; ic < 4; ++ic) {
#pragma unroll
                    for (int k = 0; k < 3; ++k) {
                        int j = ol - 1 + k;
                        if (j >= 0 && j < 16)
                            s = fmaf(sk[ic][j >> 1], w4[(oc*4 + ic)*3 + k], s);
                    }
                }
                o[oc*16 + ol] = fast_tanh(s);
            }
        }
    } else {
#pragma unroll
        for (int q = 0; q < 32; ++q) o[q] = 0.0f;
    }

    // own row read above, own row written below -> no barrier needed here
#pragma unroll
    for (int r = 0; r < 8; ++r)
        lds[t * 9 + r] = make_float4(o[4*r+0], o[4*r+1], o[4*r+2], o[4*r+3]);
    __syncthreads();

    // ---- stage out: LDS -> coalesced global ----
    float4* op = (float4*)out;
#pragma unroll
    for (int q = 0; q < 8; ++q) {
        int g = q * 256 + t;
        if (blockBase + g < f4total) {
            int s = g >> 3, r = g & 7;
            op[blockBase + g] = lds[s * 9 + r];
        }
    }
}

extern "C" void kernel_launch(void* const* d_in, const int* in_sizes, int n_in,
                              void* d_out, int out_size, void* d_ws, size_t ws_size,
                              hipStream_t stream) {
    const float* x  = (const float*)d_in[0];
    const float* w1 = (const float*)d_in[1];
    const float* b1 = (const float*)d_in[2];
    const float* w2 = (const float*)d_in[3];
    const float* b2 = (const float*)d_in[4];
    const float* w3 = (const float*)d_in[5];
    const float* b3 = (const float*)d_in[6];
    const float* w4 = (const float*)d_in[7];
    const float* b4 = (const float*)d_in[8];
    float* out = (float*)d_out;

    int n = in_sizes[0] / 32;           // B = 262144 samples
    const int block = 256;
    int grid = (n + block - 1) / block;
    hipLaunchKernelGGL(minigen_kernel, dim3(grid), dim3(block), 0, stream,
                       x, w1, b1, w2, b2, w3, b3, w4, b4, out, n);
}

// Round 3
// 106.818 us; speedup vs baseline: 1.1241x; 1.0037x over previous
//
#include <hip/hip_runtime.h>

#define SLOPE 0.2f

__device__ __forceinline__ float leaky(float v) {
    // slope < 1  =>  leaky(v) == max(v, 0.2*v)
    return __builtin_fmaxf(v, SLOPE * v);
}

__device__ __forceinline__ float fast_tanh(float v) {
    // tanh(x) = 1 - 2/(exp(2x)+1); saturates correctly at +/-1.
    float e = __expf(2.0f * v);
    return 1.0f - 2.0f * __builtin_amdgcn_rcpf(e + 1.0f);
}

// Exchange with paired lane (lane ^ 1) via DPP quad_perm [1,0,3,2]:
// pure VALU, no LDS pipe, no waitcnt.
__device__ __forceinline__ float swap1(float v) {
    int i = __builtin_bit_cast(int, v);
    i = __builtin_amdgcn_mov_dpp(i, 0xB1, 0xF, 0xF, true);
    return __builtin_bit_cast(float, i);
}

// 2 threads per sample: even lane (p=0) computes the left half of every
// layer's length dim, odd lane (p=1) the right half. Boundary (halo) values
// cross via swap1(). Doubles wave count (8192 waves -> ~7-8/SIMD) and halves
// per-thread dependency chains vs 1-thread/sample. No divergent branches:
// grid covers n exactly, so all weight loads scalarize to s_load.
__global__ __launch_bounds__(256, 6) void minigen_kernel(
    const float* __restrict__ x,
    const float* __restrict__ w1, const float* __restrict__ b1,
    const float* __restrict__ w2, const float* __restrict__ b2,
    const float* __restrict__ w3, const float* __restrict__ b3,
    const float* __restrict__ w4, const float* __restrict__ b4,
    float* __restrict__ out)
{
    __shared__ float4 lds[128 * 9];              // 128 samples x (8 f4 + pad)

    const int t = threadIdx.x;
    const int p = t & 1;                          // which half of the sample
    const int row = t >> 1;                       // local sample row in LDS
    const long long blockBase = (long long)blockIdx.x * 1024;  // f4 units

    // ---- stage in: coalesced global -> LDS (1024 f4 per block) ----
    const float4* xin = (const float4*)x;
#pragma unroll
    for (int q = 0; q < 4; ++q) {
        int g = q * 256 + t;
        float4 v = xin[blockBase + g];
        lds[(g >> 3) * 9 + (g & 7)] = v;
    }
    __syncthreads();

    // ---- own half: x[ic][p*8 + j], j=0..7 ----
    float xr[2][8];
#pragma unroll
    for (int ic = 0; ic < 2; ++ic) {
#pragma unroll
        for (int m = 0; m < 2; ++m) {
            float4 v = lds[row * 9 + ic * 4 + p * 2 + m];
            xr[ic][4*m+0] = v.x; xr[ic][4*m+1] = v.y;
            xr[ic][4*m+2] = v.z; xr[ic][4*m+3] = v.w;
        }
    }

    // ---- conv1: [2,16] -> [4,8], stride 2, pad 1, leaky ----
    // window xw[ic][0..8] = input positions (p*8-1 .. p*8+7); xw[0] is pad
    // for p=0, halo x[ic][7] for p=1.
    float xw[2][9];
#pragma unroll
    for (int ic = 0; ic < 2; ++ic) {
        float h = swap1(xr[ic][7]);
        xw[ic][0] = p ? h : 0.0f;
#pragma unroll
        for (int j = 0; j < 8; ++j) xw[ic][j+1] = xr[ic][j];
    }
    float e1h[4][4];                              // e1[oc][p*4 + l]
#pragma unroll
    for (int oc = 0; oc < 4; ++oc) {
#pragma unroll
        for (int l = 0; l < 4; ++l) {
            float s = b1[oc];
#pragma unroll
            for (int ic = 0; ic < 2; ++ic)
#pragma unroll
                for (int k = 0; k < 3; ++k)
                    s = fmaf(xw[ic][2*l + k], w1[(oc*2 + ic)*3 + k], s);
            e1h[oc][l] = leaky(s);
        }
    }

    // ---- conv2: [4,8] -> [8,4], stride 2, pad 1, leaky ----
    // window ew[ic][0..4] = e1 positions (p*4-1 .. p*4+3)
    float ew[4][5];
#pragma unroll
    for (int ic = 0; ic < 4; ++ic) {
        float h = swap1(e1h[ic][3]);
        ew[ic][0] = p ? h : 0.0f;
#pragma unroll
        for (int j = 0; j < 4; ++j) ew[ic][j+1] = e1h[ic][j];
    }
    float bnh[8][2];                              // bn[oc][p*2 + l]
#pragma unroll
    for (int oc = 0; oc < 8; ++oc) {
#pragma unroll
        for (int l = 0; l < 2; ++l) {
            float s = b2[oc];
#pragma unroll
            for (int ic = 0; ic < 4; ++ic)
#pragma unroll
                for (int k = 0; k < 3; ++k)
                    s = fmaf(ew[ic][2*l + k], w2[(oc*4 + ic)*3 + k], s);
            bnh[oc][l] = leaky(s);
        }
    }

    // ---- up1(x2) + conv3: [8,8] -> [4,8], s1 p1, leaky, + skip e1 ----
    // window bw[ic][0..5] = up1 positions (p*4-1 .. p*4+4), up1[j]=bn[j>>1]
    float bw[8][6];
#pragma unroll
    for (int ic = 0; ic < 8; ++ic) {
        float hR = swap1(bnh[ic][0]);             // p=0 receives bn[ic][2]
        float hL = swap1(bnh[ic][1]);             // p=1 receives bn[ic][1]
        bw[ic][0] = p ? hL : 0.0f;
        bw[ic][1] = bnh[ic][0]; bw[ic][2] = bnh[ic][0];
        bw[ic][3] = bnh[ic][1]; bw[ic][4] = bnh[ic][1];
        bw[ic][5] = p ? 0.0f : hR;
    }
    float skh[4][4];                              // sk[oc][p*4 + l]
#pragma unroll
    for (int oc = 0; oc < 4; ++oc) {
#pragma unroll
        for (int l = 0; l < 4; ++l) {
            float s = b3[oc];
#pragma unroll
            for (int ic = 0; ic < 8; ++ic)
#pragma unroll
                for (int k = 0; k < 3; ++k)
                    s = fmaf(bw[ic][l + k], w3[(oc*8 + ic)*3 + k], s);
            skh[oc][l] = leaky(s) + e1h[oc][l];
        }
    }

    // ---- up2(x2) + conv4: [4,16] -> [2,16], s1 p1, tanh ----
    // window sw[ic][0..9] = up2 positions (p*8-1 .. p*8+8), up2[j]=sk[j>>1]
    float sw[4][10];
#pragma unroll
    for (int ic = 0; ic < 4; ++ic) {
        float hL = swap1(skh[ic][3]);             // p=1 receives sk[ic][3]
        float hR = swap1(skh[ic][0]);             // p=0 receives sk[ic][4]
        sw[ic][0] = p ? hL : 0.0f;
        sw[ic][1] = skh[ic][0]; sw[ic][2] = skh[ic][0];
        sw[ic][3] = skh[ic][1]; sw[ic][4] = skh[ic][1];
        sw[ic][5] = skh[ic][2]; sw[ic][6] = skh[ic][2];
        sw[ic][7] = skh[ic][3]; sw[ic][8] = skh[ic][3];
        sw[ic][9] = p ? 0.0f : hR;
    }
    float oh[2][8];                               // out[oc][p*8 + l]
#pragma unroll
    for (int oc = 0; oc < 2; ++oc) {
#pragma unroll
        for (int l = 0; l < 8; ++l) {
            float s = b4[oc];
#pragma unroll
            for (int ic = 0; ic < 4; ++ic)
#pragma unroll
                for (int k = 0; k < 3; ++k)
                    s = fmaf(sw[ic][l + k], w4[(oc*4 + ic)*3 + k], s);
            oh[oc][l] = fast_tanh(s);
        }
    }

    // ---- own slots written back to LDS (same slots this thread read:
    //      no cross-thread hazard, no barrier needed before writes) ----
#pragma unroll
    for (int oc = 0; oc < 2; ++oc)
#pragma unroll
        for (int m = 0; m < 2; ++m)
            lds[row * 9 + oc * 4 + p * 2 + m] =
                make_float4(oh[oc][4*m+0], oh[oc][4*m+1],
                            oh[oc][4*m+2], oh[oc][4*m+3]);
    __syncthreads();

    // ---- stage out: LDS -> coalesced global ----
    float4* op = (float4*)out;
#pragma unroll
    for (int q = 0; q < 4; ++q) {
        int g = q * 256 + t;
        op[blockBase + g] = lds[(g >> 3) * 9 + (g & 7)];
    }
}

extern "C" void kernel_launch(void* const* d_in, const int* in_sizes, int n_in,
                              void* d_out, int out_size, void* d_ws, size_t ws_size,
                              hipStream_t stream) {
    const float* x  = (const float*)d_in[0];
    const float* w1 = (const float*)d_in[1];
    const float* b1 = (const float*)d_in[2];
    const float* w2 = (const float*)d_in[3];
    const float* b2 = (const float*)d_in[4];
    const float* w3 = (const float*)d_in[5];
    const float* b3 = (const float*)d_in[6];
    const float* w4 = (const float*)d_in[7];
    const float* b4 = (const float*)d_in[8];
    float* out = (float*)d_out;

    int n = in_sizes[0] / 32;           // B = 262144 samples, 128 per block
    int grid = n / 128;                  // exact: 262144 % 128 == 0
    hipLaunchKernelGGL(minigen_kernel, dim3(grid), dim3(256), 0, stream,
                       x, w1, b1, w2, b2, w3, b3, w4, b4, out);
}